// Round 4
// baseline (18.294 us; speedup 1.0000x reference)
//
#include <hip/hip_runtime.h>
#include <hip/hip_fp16.h>

// AverageSpanExtractor via blocked prefix sums.
// out[b,n,:] = mean(seq[b, start:end, :]), width = end-start in [1,32].
//
// Pass 1: per (b, blk=32 rows): inclusive prefixes Q[b][blk][j][d] (fp16),
//         computed by a 4-wave workgroup scan (8 rows/wave + LDS offset
//         exchange) -> 4096 waves (16/CU) instead of 1024 (4/CU).
// Pass 2: span covers <=2 blocks: sum = Q[blkB][jb] + (cross? Q[blkA][31])
//         - (ja>0? Q[blkA][ja-1]); out = sum/w. 8192 waves (32/CU).

constexpr int B = 8;
constexpr int S = 4096;
constexpr int D = 256;
constexpr int N_SPANS = 1024;
constexpr int BLK = 32;
constexpr int NBLK = S / BLK;              // 128
constexpr int TOTAL_SPANS = B * N_SPANS;   // 8192
constexpr int TOTAL_QBLOCKS = B * NBLK;    // 1024

// ---------------- Pass 1: 4-wave blocked scan, fp32 acc -> fp16 store --------
__global__ __launch_bounds__(256) void block_prefix_scan_kernel(
    const float* __restrict__ seq,   // [B, S, D]
    __half*      __restrict__ Q)     // [B, NBLK, BLK, D]
{
    const int gid  = blockIdx.x;          // one workgroup per (b, blk)
    const int wv   = threadIdx.x >> 6;    // 0..3, owns rows 8*wv .. 8*wv+7
    const int lane = threadIdx.x & 63;    // owns 4 consecutive d's (float4)
    const int b    = gid >> 7;            // / NBLK
    const int blk  = gid & (NBLK - 1);

    __shared__ float4 totals[4][64];      // per-wave totals, 4 KB

    const float4* src = reinterpret_cast<const float4*>(
        seq + (size_t)(b * S + blk * BLK + wv * 8) * D) + lane;

    float4 p[8];
    float4 acc = make_float4(0.f, 0.f, 0.f, 0.f);
    #pragma unroll
    for (int j = 0; j < 8; ++j) {
        float4 v = src[(size_t)j * (D / 4)];
        acc.x += v.x; acc.y += v.y; acc.z += v.z; acc.w += v.w;
        p[j] = acc;
    }
    totals[wv][lane] = acc;
    __syncthreads();

    float4 off = make_float4(0.f, 0.f, 0.f, 0.f);
    #pragma unroll
    for (int w2 = 0; w2 < 3; ++w2) {
        if (w2 < wv) {                    // wave-uniform condition
            float4 t = totals[w2][lane];
            off.x += t.x; off.y += t.y; off.z += t.z; off.w += t.w;
        }
    }

    __half* qbase = Q + ((size_t)gid * BLK + wv * 8) * D + lane * 4;
    #pragma unroll
    for (int j = 0; j < 8; ++j) {
        float4 s = p[j];
        s.x += off.x; s.y += off.y; s.z += off.z; s.w += off.w;
        union { __half2 h[2]; uint2 u; } pk;
        pk.h[0] = __floats2half2_rn(s.x, s.y);
        pk.h[1] = __floats2half2_rn(s.z, s.w);
        *reinterpret_cast<uint2*>(qbase + (size_t)j * D) = pk.u; // 8B/lane
    }
}

// ---------------- Pass 2: span mean from 2-3 prefix rows ---------------------
__global__ __launch_bounds__(256) void span_from_prefix_kernel(
    const __half* __restrict__ Q,     // [B, NBLK, BLK, D]
    const int*    __restrict__ idx32, // [B, N_SPANS, 2] int32 (or int64)
    float*        __restrict__ out)   // [B, N_SPANS, D]
{
    const int span = (blockIdx.x * blockDim.x + threadIdx.x) >> 6;
    const int lane = threadIdx.x & 63;
    if (span >= TOTAL_SPANS) return;

    // int32-first read; detect int64 layout (high word => end<=start).
    int start = idx32[2 * span + 0];
    int end   = idx32[2 * span + 1];
    if (end <= start) {
        const long long* idx64 = reinterpret_cast<const long long*>(idx32);
        start = (int)idx64[2 * span + 0];
        end   = (int)idx64[2 * span + 1];
    }
    start = __builtin_amdgcn_readfirstlane(start);
    end   = __builtin_amdgcn_readfirstlane(end);
    const int w = end - start;
    const int b = span >> 10;

    const int blkA = start >> 5, ja = start & 31;
    const int e    = end - 1;
    const int blkB = e >> 5,     jb = e & 31;   // inclusive prefix index

    const __half* qb = Q + (size_t)b * NBLK * BLK * D + lane * 4;

    auto load4 = [&](int blk, int j) -> float4 {
        union { uint2 u; __half2 h[2]; } pk;
        pk.u = *reinterpret_cast<const uint2*>(qb + (size_t)(blk * BLK + j) * D);
        float2 f01 = __half22float2(pk.h[0]);
        float2 f23 = __half22float2(pk.h[1]);
        return make_float4(f01.x, f01.y, f23.x, f23.y);
    };

    float4 s = load4(blkB, jb);
    if (blkB > blkA) {                  // cross-block: add blkA total
        float4 t = load4(blkA, BLK - 1);
        s.x += t.x; s.y += t.y; s.z += t.z; s.w += t.w;
    }
    if (ja > 0) {                       // subtract prefix before start
        float4 t = load4(blkA, ja - 1);
        s.x -= t.x; s.y -= t.y; s.z -= t.z; s.w -= t.w;
    }

    const float inv = 1.0f / (float)w;
    s.x *= inv; s.y *= inv; s.z *= inv; s.w *= inv;
    reinterpret_cast<float4*>(out + (size_t)span * D)[lane] = s;
}

extern "C" void kernel_launch(void* const* d_in, const int* in_sizes, int n_in,
                              void* d_out, int out_size, void* d_ws, size_t ws_size,
                              hipStream_t stream) {
    const float* seq = (const float*)d_in[0];
    const int*   idx = (const int*)d_in[1];
    float*       out = (float*)d_out;
    __half*      Q   = (__half*)d_ws;   // 16 MB of workspace

    // Pass 1: one 256-thread block per (b, blk) -> 1024 blocks, 4096 waves
    block_prefix_scan_kernel<<<TOTAL_QBLOCKS, 256, 0, stream>>>(seq, Q);
    // Pass 2: 8192 waves = 2048 blocks x 4 waves
    span_from_prefix_kernel<<<TOTAL_SPANS / 4, 256, 0, stream>>>(Q, idx, out);
}

// Round 5
// 13.880 us; speedup vs baseline: 1.3180x; 1.3180x over previous
//
#include <hip/hip_runtime.h>
#include <hip/hip_fp16.h>

// AverageSpanExtractor, single fused kernel.
// out[b,n,:] = mean(seq[b, start:end, :]), width in [1,32].
//
// width<=32 => span covers at most blocks {blkA, blkA+1} (32-row blocks).
// One workgroup per (b, blkA-candidate): loads 64 rows (own block + next),
// builds both 32-row inclusive fp16 prefixes in LDS, finds all spans of its
// batch starting in its block (~8 avg), serves each with 2-3 LDS reads + one
// coalesced 1 KB store. No intermediate global buffer, no atomics, 1 dispatch.
//
// start <= S-MAX_WIDTH-1 = 4063 => blkA <= 126, so next block always exists
// for any served span; blk==127's next-half loads are clamped and unused.

constexpr int B = 8;
constexpr int S = 4096;
constexpr int D = 256;
constexpr int N_SPANS = 1024;
constexpr int BLK = 32;
constexpr int NBLK = S / BLK;          // 128
constexpr int NWG = B * NBLK;          // 1024 workgroups
constexpr int LIST_CAP = 128;          // avg occupancy ~8, binomial tail << 1e-15

__device__ __forceinline__ float4 f4add(float4 a, float4 b) {
    a.x += b.x; a.y += b.y; a.z += b.z; a.w += b.w; return a;
}

__global__ __launch_bounds__(256) void fused_span_avg_kernel(
    const float* __restrict__ seq,   // [B, S, D]
    const int*   __restrict__ idx32, // [B, N_SPANS, 2] int32 (or int64)
    float*       __restrict__ out)   // [B, N_SPANS, D]
{
    const int gid  = blockIdx.x;
    const int b    = gid & (B - 1);   // batch = dispatch%8 -> per-XCD L2 locality
    const int blk  = gid >> 3;        // 0..127
    const int tid  = threadIdx.x;
    const int wv   = tid >> 6;        // 0..3; waves 0-1: own block, 2-3: next block
    const int lane = tid & 63;        // lane owns d = 4*lane .. 4*lane+3

    __shared__ uint2  Pfx[2][BLK][64];   // fp16x4 inclusive prefixes (own,next), 32 KB
    __shared__ float4 totals[4][64];     // per-wave 16-row totals, 4 KB
    __shared__ unsigned list[LIST_CAP];  // packed span descriptors
    __shared__ int count;

    // ---- phase 1a: load my 16 rows (independent loads, all in flight) ----
    const int row0 = blk * BLK + wv * 16;          // global row of my first row
    float4 p[16];
    #pragma unroll
    for (int j = 0; j < 16; ++j) {
        int r = row0 + j; if (r > S - 1) r = S - 1;  // clamp only for blk==127 next-half
        p[j] = *((const float4*)(seq + ((size_t)b * S + r) * D) + lane);
    }

    if (tid == 0) count = 0;
    __syncthreads();

    // ---- phase 2: scan batch's spans, compact those starting in my block ----
    #pragma unroll
    for (int k = 0; k < 4; ++k) {
        const int n = tid + k * 256;
        const size_t base = ((size_t)b * N_SPANS + n) * 2;
        int start = idx32[base + 0];
        int end   = idx32[base + 1];
        if (end <= start) {                          // int64 layout fallback
            const long long* idx64 = (const long long*)idx32;
            start = (int)idx64[base + 0];
            end   = (int)idx64[base + 1];
        }
        if ((start >> 5) == blk) {
            const int w     = end - start;           // 1..32
            const int ja    = start & 31;
            const int e     = end - 1;
            const int cross = ((e >> 5) != blk) ? 1 : 0;
            const int jb    = e & 31;                // prefix row (own or next)
            const unsigned pk = (unsigned)n | ((unsigned)ja << 10) |
                                ((unsigned)jb << 15) | ((unsigned)cross << 20) |
                                ((unsigned)(w - 1) << 21);
            const int slot = atomicAdd(&count, 1);
            if (slot < LIST_CAP) list[slot] = pk;
        }
    }

    // ---- phase 1b: in-register inclusive prefix over my 16 rows ----
    #pragma unroll
    for (int j = 1; j < 16; ++j) p[j] = f4add(p[j], p[j - 1]);
    totals[wv][lane] = p[15];
    __syncthreads();                                 // totals + list complete

    const int sel = wv >> 1;                         // 0 = own block, 1 = next
    float4 off = make_float4(0.f, 0.f, 0.f, 0.f);
    if (wv & 1) off = totals[sel * 2][lane];         // add first-half total

    #pragma unroll
    for (int j = 0; j < 16; ++j) {
        const float4 s = f4add(p[j], off);
        union { __half2 h[2]; uint2 u; } pk2;
        pk2.h[0] = __floats2half2_rn(s.x, s.y);
        pk2.h[1] = __floats2half2_rn(s.z, s.w);
        Pfx[sel][(wv & 1) * 16 + j][lane] = pk2.u;   // 8B/lane, 2-way bank alias (free)
    }
    __syncthreads();                                 // Pfx ready

    // ---- phase 3: serve spans (each wave takes entries round-robin) ----
    auto rd = [&](int selr, int j) -> float4 {
        union { uint2 u; __half2 h[2]; } pk2;
        pk2.u = Pfx[selr][j][lane];
        const float2 a = __half22float2(pk2.h[0]);
        const float2 c = __half22float2(pk2.h[1]);
        return make_float4(a.x, a.y, c.x, c.y);
    };

    const int cnt = (count < LIST_CAP) ? count : LIST_CAP;
    for (int i = wv; i < cnt; i += 4) {
        const unsigned e = list[i];
        const int n     = e & 1023;
        const int ja    = (e >> 10) & 31;
        const int jb    = (e >> 15) & 31;
        const int cross = (e >> 20) & 1;
        const int w     = (int)((e >> 21) & 31) + 1;

        float4 s = rd(cross, jb);                    // prefix up to span end
        if (cross) s = f4add(s, rd(0, BLK - 1));     // + own-block total
        if (ja) {                                    // - prefix before start
            const float4 t = rd(0, ja - 1);
            s.x -= t.x; s.y -= t.y; s.z -= t.z; s.w -= t.w;
        }
        const float inv = 1.0f / (float)w;
        s.x *= inv; s.y *= inv; s.z *= inv; s.w *= inv;
        *((float4*)(out + ((size_t)b * N_SPANS + n) * D) + lane) = s;
    }
}

extern "C" void kernel_launch(void* const* d_in, const int* in_sizes, int n_in,
                              void* d_out, int out_size, void* d_ws, size_t ws_size,
                              hipStream_t stream) {
    const float* seq = (const float*)d_in[0];
    const int*   idx = (const int*)d_in[1];
    float*       out = (float*)d_out;

    fused_span_avg_kernel<<<NWG, 256, 0, stream>>>(seq, idx, out);
}

// Round 6
// 13.825 us; speedup vs baseline: 1.3232x; 1.0039x over previous
//
#include <hip/hip_runtime.h>
#include <hip/hip_fp16.h>

// AverageSpanExtractor, single fused kernel (R5: barrier reorder + branchless idx).
// out[b,n,:] = mean(seq[b, start:end, :]), width in [1,32].
//
// width<=32 => span covers at most blocks {blkA, blkA+1} (32-row blocks).
// One workgroup per (b, blkA): loads 64 rows (own block + next), builds both
// 32-row inclusive fp16 prefixes in LDS, finds all spans of its batch starting
// in its block (~8 avg), serves each with 2-3 LDS reads + one 1 KB store.
//
// R5 changes vs R4:
//  - count=0 barrier moved BEFORE the seq loads: __syncthreads() emits
//    s_waitcnt vmcnt(0) (HIP compiler), which in R4 drained all 16 in-flight
//    row loads before the span scan could hide their latency.
//  - idx layout (int32 vs int64) detected once from idx32[1] (int32-layout end
//    is always >=1; int64-layout high word is always 0) -> each span is ONE
//    independent load, not a dependent load->compare->reload chain.
//  - per-row clamp replaced by hoisted row0 = min(row0, S-16) (only affects
//    block 127's never-read next-half prefix).

constexpr int B = 8;
constexpr int S = 4096;
constexpr int D = 256;
constexpr int N_SPANS = 1024;
constexpr int BLK = 32;
constexpr int NBLK = S / BLK;          // 128
constexpr int NWG = B * NBLK;          // 1024 workgroups
constexpr int LIST_CAP = 128;          // avg occupancy ~8; binomial tail << 1e-15

__device__ __forceinline__ float4 f4add(float4 a, float4 b) {
    a.x += b.x; a.y += b.y; a.z += b.z; a.w += b.w; return a;
}

__global__ __launch_bounds__(256) void fused_span_avg_kernel(
    const float* __restrict__ seq,   // [B, S, D]
    const int*   __restrict__ idx32, // [B, N_SPANS, 2] int32 or int64 words
    float*       __restrict__ out)   // [B, N_SPANS, D]
{
    const int gid  = blockIdx.x;
    const int b    = gid & (B - 1);   // batch = blockIdx%8 -> per-XCD L2 slab
    const int blk  = gid >> 3;        // 0..127
    const int tid  = threadIdx.x;
    const int wv   = tid >> 6;        // 0..3; waves 0-1: own block, 2-3: next
    const int lane = tid & 63;        // lane owns d = 4*lane .. 4*lane+3

    __shared__ uint2  Pfx[2][BLK][64];   // fp16x4 inclusive prefixes, 32 KB
    __shared__ float4 totals[4][64];     // per-wave 16-row totals, 4 KB
    __shared__ unsigned list[LIST_CAP];  // packed span descriptors
    __shared__ int count;

    // ---- init shared counter while NOTHING is in flight (cheap drain) ----
    if (tid == 0) count = 0;
    __syncthreads();

    // ---- phase 1a: issue my 16 row loads (stay in flight through phase 2) --
    int row0 = blk * BLK + wv * 16;
    if (row0 > S - 16) row0 = S - 16;      // blk==127 next-half only (unused)
    const float4* src = reinterpret_cast<const float4*>(
        seq + ((size_t)b * S + row0) * D) + lane;
    float4 p[16];
    #pragma unroll
    for (int j = 0; j < 16; ++j) p[j] = src[(size_t)j * (D / 4)];

    // ---- phase 2: scan batch's spans, compact those starting in my block --
    // Uniform one-time layout detection: int32-layout word1 = end(span0) >= 1;
    // int64-layout word1 = high word of start = 0.
    const bool is64 = (idx32[1] == 0);
    #pragma unroll
    for (int k = 0; k < 4; ++k) {
        const int n = tid + k * 256;
        int start, end;
        if (is64) {
            const int4 wds = *((const int4*)idx32 + ((size_t)b * N_SPANS + n));
            start = wds.x; end = wds.z;        // lo words of the two int64s
        } else {
            const int2 wds = *((const int2*)idx32 + ((size_t)b * N_SPANS + n));
            start = wds.x; end = wds.y;
        }
        if ((start >> 5) == blk) {
            const int w     = end - start;     // 1..32
            const int ja    = start & 31;
            const int e     = end - 1;
            const int cross = ((e >> 5) != blk) ? 1 : 0;
            const int jb    = e & 31;
            const unsigned pk = (unsigned)n | ((unsigned)ja << 10) |
                                ((unsigned)jb << 15) | ((unsigned)cross << 20) |
                                ((unsigned)(w - 1) << 21);
            const int slot = atomicAdd(&count, 1);
            if (slot < LIST_CAP) list[slot] = pk;
        }
    }

    // ---- phase 1b: in-register inclusive prefix over my 16 rows ----
    #pragma unroll
    for (int j = 1; j < 16; ++j) p[j] = f4add(p[j], p[j - 1]);
    totals[wv][lane] = p[15];
    __syncthreads();                           // totals + list complete

    const int sel = wv >> 1;                   // 0 = own block, 1 = next
    float4 off = make_float4(0.f, 0.f, 0.f, 0.f);
    if (wv & 1) off = totals[wv - 1][lane];    // add first-half total

    #pragma unroll
    for (int j = 0; j < 16; ++j) {
        const float4 s = f4add(p[j], off);
        union { __half2 h[2]; uint2 u; } pk2;
        pk2.h[0] = __floats2half2_rn(s.x, s.y);
        pk2.h[1] = __floats2half2_rn(s.z, s.w);
        Pfx[sel][(wv & 1) * 16 + j][lane] = pk2.u;   // 8B/lane, 2-way alias (free)
    }
    __syncthreads();                           // Pfx ready

    // ---- phase 3: serve spans (waves take entries round-robin) ----
    auto rd = [&](int selr, int j) -> float4 {
        union { uint2 u; __half2 h[2]; } pk2;
        pk2.u = Pfx[selr][j][lane];
        const float2 a = __half22float2(pk2.h[0]);
        const float2 c = __half22float2(pk2.h[1]);
        return make_float4(a.x, a.y, c.x, c.y);
    };

    const int cnt = (count < LIST_CAP) ? count : LIST_CAP;
    for (int i = wv; i < cnt; i += 4) {
        const unsigned e = list[i];
        const int n     = e & 1023;
        const int ja    = (e >> 10) & 31;
        const int jb    = (e >> 15) & 31;
        const int cross = (e >> 20) & 1;
        const int w     = (int)((e >> 21) & 31) + 1;

        float4 s = rd(cross, jb);                    // prefix up to span end
        if (cross) s = f4add(s, rd(0, BLK - 1));     // + own-block total
        if (ja) {                                    // - prefix before start
            const float4 t = rd(0, ja - 1);
            s.x -= t.x; s.y -= t.y; s.z -= t.z; s.w -= t.w;
        }
        const float inv = 1.0f / (float)w;
        s.x *= inv; s.y *= inv; s.z *= inv; s.w *= inv;
        *((float4*)(out + ((size_t)b * N_SPANS + n) * D) + lane) = s;
    }
}

extern "C" void kernel_launch(void* const* d_in, const int* in_sizes, int n_in,
                              void* d_out, int out_size, void* d_ws, size_t ws_size,
                              hipStream_t stream) {
    const float* seq = (const float*)d_in[0];
    const int*   idx = (const int*)d_in[1];
    float*       out = (float*)d_out;

    fused_span_avg_kernel<<<NWG, 256, 0, stream>>>(seq, idx, out);
}

// Round 7
// 13.201 us; speedup vs baseline: 1.3858x; 1.0473x over previous
//
#include <hip/hip_runtime.h>
#include <hip/hip_fp16.h>

// AverageSpanExtractor, single fused kernel (R6: 128-row chunks, serve-96).
// out[b,n,:] = mean(seq[b, start:end, :]), width in [1,32].
//
// Traffic model (fits R0/R4/R5 exactly): dur ~= total_traffic / 6.4 TB/s.
// R4 traffic: 64 MB seq (2x amp) + 16 MB idx re-reads + 8.4 MB out = 88 MB -> 13.8 us.
// R6: WG loads 128 rows, serves spans STARTING in its first 96 rows (w<=32 =>
// span contained). 43 chunks/batch -> seq amp 1.33x (43 MB), idx re-reads
// 344*16KB = 5.5 MB, out 8.4 MB => ~57 MB -> ~9.5 us predicted.
//
// Precision: fp16 prefixes re-based per 32-row SUB-block (4 subs/chunk);
// span crosses <=1 sub boundary -> same 3-read combine as R4 (absmax 0.0156).

constexpr int B = 8;
constexpr int S = 4096;
constexpr int D = 256;
constexpr int N_SPANS = 1024;
constexpr int SUB = 32;                 // fp16 prefix re-base granularity
constexpr int SERVE = 96;               // starts served per chunk
constexpr int NCHUNK = 43;              // ceil(4064/96); covers starts 0..4127
constexpr int NWG = B * NCHUNK;         // 344 workgroups
constexpr int LIST_CAP = 192;           // mean 24 spans/chunk, sd ~4.8

__device__ __forceinline__ float4 f4add(float4 a, float4 b) {
    a.x += b.x; a.y += b.y; a.z += b.z; a.w += b.w; return a;
}

__global__ __launch_bounds__(512, 4) void fused_span_avg_kernel(
    const float* __restrict__ seq,   // [B, S, D]
    const int*   __restrict__ idx32, // [B, N_SPANS, 2] int32 or int64 words
    float*       __restrict__ out)   // [B, N_SPANS, D]
{
    const int gid  = blockIdx.x;
    const int b    = gid & (B - 1);      // batch = gid%8 -> per-XCD L2 slab
    const int c    = gid >> 3;           // chunk 0..42
    const int tid  = threadIdx.x;
    const int wv   = tid >> 6;           // 0..7, owns 16 rows
    const int lane = tid & 63;           // owns d = 4*lane .. 4*lane+3

    __shared__ uint2  Pfx[4][SUB][64];   // fp16x4 prefixes per sub-block, 64 KB
    __shared__ float4 totals[8][64];     // per-wave 16-row totals, 8 KB
    __shared__ unsigned list[LIST_CAP];
    __shared__ int count;

    // init counter while nothing is in flight (barrier drain is free here)
    if (tid == 0) count = 0;
    __syncthreads();

    // ---- phase 1a: issue my 16 row loads (in flight through the idx scan) --
    const int base_start = c * SERVE;
    int row0 = base_start + wv * 16;
    if (row0 > S - 16) row0 = S - 16;    // only chunk 42's subs 2-3 (never read)
    const float4* src = reinterpret_cast<const float4*>(
        seq + ((size_t)b * S + row0) * D) + lane;
    float4 p[16];
    #pragma unroll
    for (int j = 0; j < 16; ++j) p[j] = src[(size_t)j * (D / 4)];

    // ---- phase 2: scan batch's 1024 spans, keep those starting in [base, base+96) --
    const bool is64 = (idx32[1] == 0);   // int32-layout word1 = end(span0) >= 1
    #pragma unroll
    for (int k = 0; k < 2; ++k) {
        const int n = tid + k * 512;
        int start, end;
        if (is64) {
            const int4 wds = *((const int4*)idx32 + ((size_t)b * N_SPANS + n));
            start = wds.x; end = wds.z;  // lo words of the two int64s
        } else {
            const int2 wds = *((const int2*)idx32 + ((size_t)b * N_SPANS + n));
            start = wds.x; end = wds.y;
        }
        const int rs = start - base_start;
        if ((unsigned)rs < (unsigned)SERVE) {
            const int w  = end - start;          // 1..32
            const int jb = rs + w - 1;           // 0..126 (< 128)
            const unsigned pk = (unsigned)n | ((unsigned)rs << 10) |
                                ((unsigned)jb << 17) | ((unsigned)(w - 1) << 24);
            const int slot = atomicAdd(&count, 1);
            if (slot < LIST_CAP) list[slot] = pk;
        }
    }

    // ---- phase 1b: in-register inclusive prefix over my 16 rows ----
    #pragma unroll
    for (int j = 1; j < 16; ++j) p[j] = f4add(p[j], p[j - 1]);
    totals[wv][lane] = p[15];
    __syncthreads();                     // totals + list complete

    // waves (2s, 2s+1) form sub-block s; odd wave adds partner's total
    float4 off = make_float4(0.f, 0.f, 0.f, 0.f);
    if (wv & 1) off = totals[wv - 1][lane];
    const int sub = wv >> 1;

    #pragma unroll
    for (int j = 0; j < 16; ++j) {
        const float4 s = f4add(p[j], off);
        union { __half2 h[2]; uint2 u; } pk2;
        pk2.h[0] = __floats2half2_rn(s.x, s.y);
        pk2.h[1] = __floats2half2_rn(s.z, s.w);
        Pfx[sub][(wv & 1) * 16 + j][lane] = pk2.u;  // 8B/lane, 2-way alias (free)
    }
    __syncthreads();                     // Pfx ready

    // ---- phase 3: serve spans (8 waves round-robin) ----
    auto rd = [&](int s_, int j) -> float4 {
        union { uint2 u; __half2 h[2]; } pk2;
        pk2.u = Pfx[s_][j][lane];
        const float2 a = __half22float2(pk2.h[0]);
        const float2 cc = __half22float2(pk2.h[1]);
        return make_float4(a.x, a.y, cc.x, cc.y);
    };

    const int cnt = (count < LIST_CAP) ? count : LIST_CAP;
    for (int i = wv; i < cnt; i += 8) {
        const unsigned e = list[i];
        const int n  = e & 1023;
        const int ja = (e >> 10) & 127;          // 0..95
        const int jb = (e >> 17) & 127;          // 0..126
        const int w  = (int)((e >> 24) & 31) + 1;
        const int subA = ja >> 5, ia = ja & 31;
        const int subB = jb >> 5, ib = jb & 31;

        float4 s = rd(subB, ib);                 // prefix up to span end
        if (subB > subA) s = f4add(s, rd(subA, SUB - 1));  // + subA total
        if (ia) {                                // - prefix before start
            const float4 t = rd(subA, ia - 1);
            s.x -= t.x; s.y -= t.y; s.z -= t.z; s.w -= t.w;
        }
        const float inv = 1.0f / (float)w;
        s.x *= inv; s.y *= inv; s.z *= inv; s.w *= inv;
        *((float4*)(out + ((size_t)b * N_SPANS + n) * D) + lane) = s;
    }
}

extern "C" void kernel_launch(void* const* d_in, const int* in_sizes, int n_in,
                              void* d_out, int out_size, void* d_ws, size_t ws_size,
                              hipStream_t stream) {
    const float* seq = (const float*)d_in[0];
    const int*   idx = (const int*)d_in[1];
    float*       out = (float*)d_out;

    fused_span_avg_kernel<<<NWG, 512, 0, stream>>>(seq, idx, out);
}

// Round 9
// 11.961 us; speedup vs baseline: 1.5294x; 1.1037x over previous
//
#include <hip/hip_runtime.h>
#include <hip/hip_fp16.h>

// AverageSpanExtractor, single fused kernel (R8 = R7 with compile fix).
// out[b,n,:] = mean(seq[b, start:end, :]), width in [1,32].
//
// R7/R8 changes vs R6 (latency/residency, not traffic):
//  - idx loads issued BEFORE the 16 seq row loads. vmcnt is ordered: waiting
//    on the idx values previously required draining all older seq loads, so
//    the span scan never overlapped the 128 KB/WG seq load. Now the idx wait
//    covers only the oldest 2 loads (idx) and phase 2 hides seq latency.
//  - out stores are nontemporal (native ext_vector float4 — the HIP class
//    version doesn't compile): 8.4 MB streaming writes no longer evict the
//    L2-resident seq slabs (b == gid&7 == XCD, 4 MB/L2).

constexpr int B = 8;
constexpr int S = 4096;
constexpr int D = 256;
constexpr int N_SPANS = 1024;
constexpr int SUB = 32;                 // fp16 prefix re-base granularity
constexpr int SERVE = 96;               // starts served per chunk
constexpr int NCHUNK = 43;              // ceil(4064/96)
constexpr int NWG = B * NCHUNK;         // 344 workgroups
constexpr int LIST_CAP = 192;           // mean 24 spans/chunk

typedef float vfloat4 __attribute__((ext_vector_type(4)));

__device__ __forceinline__ float4 f4add(float4 a, float4 b) {
    a.x += b.x; a.y += b.y; a.z += b.z; a.w += b.w; return a;
}

__global__ __launch_bounds__(512, 4) void fused_span_avg_kernel(
    const float* __restrict__ seq,   // [B, S, D]
    const int*   __restrict__ idx32, // [B, N_SPANS, 2] int32 or int64 words
    float*       __restrict__ out)   // [B, N_SPANS, D]
{
    const int gid  = blockIdx.x;
    const int b    = gid & (B - 1);      // batch = gid%8 -> per-XCD L2 slab
    const int c    = gid >> 3;           // chunk 0..42
    const int tid  = threadIdx.x;
    const int wv   = tid >> 6;           // 0..7, owns 16 rows
    const int lane = tid & 63;           // owns d = 4*lane .. 4*lane+3

    __shared__ uint2  Pfx[4][SUB][64];   // fp16x4 prefixes per sub-block, 64 KB
    __shared__ float4 totals[8][64];     // per-wave 16-row totals, 8 KB
    __shared__ unsigned list[LIST_CAP];
    __shared__ int count;

    if (tid == 0) count = 0;
    __syncthreads();                     // nothing in flight; drain is free

    // ---- issue idx loads FIRST (oldest in vmcnt queue) ----
    const bool is64 = (idx32[1] == 0);   // int32-layout word1 = end(span0) >= 1
    int4 w0, w1;                         // raw words for the 2 spans this thread owns
    {
        const size_t s0 = (size_t)b * N_SPANS + tid;
        const size_t s1 = s0 + 512;
        if (is64) {
            w0 = *((const int4*)idx32 + s0);
            w1 = *((const int4*)idx32 + s1);
        } else {
            const int2 a0 = *((const int2*)idx32 + s0);
            const int2 a1 = *((const int2*)idx32 + s1);
            w0 = make_int4(a0.x, 0, a0.y, 0);
            w1 = make_int4(a1.x, 0, a1.y, 0);
        }
    }

    // ---- then issue my 16 seq row loads (younger; not drained by idx use) --
    const int base_start = c * SERVE;
    int row0 = base_start + wv * 16;
    if (row0 > S - 16) row0 = S - 16;    // chunk 42 subs 2-3 only (never read)
    const float4* src = reinterpret_cast<const float4*>(
        seq + ((size_t)b * S + row0) * D) + lane;
    float4 p[16];
    #pragma unroll
    for (int j = 0; j < 16; ++j) p[j] = src[(size_t)j * (D / 4)];

    // ---- phase 2: filter my 2 spans (consumes only idx words) ----
    #pragma unroll
    for (int k = 0; k < 2; ++k) {
        const int n     = tid + k * 512;
        const int start = k ? w1.x : w0.x;
        const int end   = k ? w1.z : w0.z;
        const int rs    = start - base_start;
        if ((unsigned)rs < (unsigned)SERVE) {
            const int w  = end - start;          // 1..32
            const int jb = rs + w - 1;           // 0..126
            const unsigned pk = (unsigned)n | ((unsigned)rs << 10) |
                                ((unsigned)jb << 17) | ((unsigned)(w - 1) << 24);
            const int slot = atomicAdd(&count, 1);
            if (slot < LIST_CAP) list[slot] = pk;
        }
    }

    // ---- phase 1b: in-register inclusive prefix over my 16 rows ----
    #pragma unroll
    for (int j = 1; j < 16; ++j) p[j] = f4add(p[j], p[j - 1]);
    totals[wv][lane] = p[15];
    __syncthreads();                     // totals + list complete

    float4 off = make_float4(0.f, 0.f, 0.f, 0.f);
    if (wv & 1) off = totals[wv - 1][lane];
    const int sub = wv >> 1;

    #pragma unroll
    for (int j = 0; j < 16; ++j) {
        const float4 s = f4add(p[j], off);
        union { __half2 h[2]; uint2 u; } pk2;
        pk2.h[0] = __floats2half2_rn(s.x, s.y);
        pk2.h[1] = __floats2half2_rn(s.z, s.w);
        Pfx[sub][(wv & 1) * 16 + j][lane] = pk2.u;  // 8B/lane, 2-way alias (free)
    }
    __syncthreads();                     // Pfx ready

    // ---- phase 3: serve spans (8 waves round-robin) ----
    auto rd = [&](int s_, int j) -> float4 {
        union { uint2 u; __half2 h[2]; } pk2;
        pk2.u = Pfx[s_][j][lane];
        const float2 a = __half22float2(pk2.h[0]);
        const float2 cc = __half22float2(pk2.h[1]);
        return make_float4(a.x, a.y, cc.x, cc.y);
    };

    const int cnt = (count < LIST_CAP) ? count : LIST_CAP;
    for (int i = wv; i < cnt; i += 8) {
        const unsigned e = list[i];
        const int n  = e & 1023;
        const int ja = (e >> 10) & 127;
        const int jb = (e >> 17) & 127;
        const int w  = (int)((e >> 24) & 31) + 1;
        const int subA = ja >> 5, ia = ja & 31;
        const int subB = jb >> 5, ib = jb & 31;

        float4 s = rd(subB, ib);
        if (subB > subA) s = f4add(s, rd(subA, SUB - 1));
        if (ia) {
            const float4 t = rd(subA, ia - 1);
            s.x -= t.x; s.y -= t.y; s.z -= t.z; s.w -= t.w;
        }
        const float inv = 1.0f / (float)w;
        vfloat4 sv;
        sv.x = s.x * inv; sv.y = s.y * inv; sv.z = s.z * inv; sv.w = s.w * inv;
        vfloat4* dst = (vfloat4*)(out + ((size_t)b * N_SPANS + n) * D) + lane;
        __builtin_nontemporal_store(sv, dst);   // don't evict seq from L2
    }
}

extern "C" void kernel_launch(void* const* d_in, const int* in_sizes, int n_in,
                              void* d_out, int out_size, void* d_ws, size_t ws_size,
                              hipStream_t stream) {
    const float* seq = (const float*)d_in[0];
    const int*   idx = (const int*)d_in[1];
    float*       out = (float*)d_out;

    fused_span_avg_kernel<<<NWG, 512, 0, stream>>>(seq, idx, out);
}

// Round 10
// 11.157 us; speedup vs baseline: 1.6397x; 1.0721x over previous
//
#include <hip/hip_runtime.h>
#include <hip/hip_fp16.h>

// AverageSpanExtractor, single fused kernel (R9: serve-128/load-160 chunks).
// out[b,n,:] = mean(seq[b, start:end, :]), width in [1,32].
//
// Cold-HBM model (caches wiped by harness 256MB fill between replays):
// floor = (32 MB seq + 8.4 MB out)/6.4 TB/s + tails + launch ~= 9.5-10.5 us.
// R9 cuts seq amplification 1.33x -> 1.25x (serve 128 starts, load 160 rows)
// and idx re-scan 5.5 -> 4 MB (256 WGs x 16 KB). 640 thr = 10 waves x 16 rows;
// LDS ~90.5 KB -> exactly 1 WG/CU (256 WGs on 256 CUs).
//
// Precision: fp16 prefixes re-based per 32-row sub-block (5 subs/chunk);
// span crosses <=1 sub boundary -> 3-read combine, absmax stays 0.0156.
// Geometry: starts <= S-33=4063 => chunk 31 serves rs<=95, jb<=126 (sub<=3);
// its clamped rows (>=4096) land only in unused sub 4. Other chunks reach at
// most row c*128+158 <= 3998 < 4096.

constexpr int B = 8;
constexpr int S = 4096;
constexpr int D = 256;
constexpr int N_SPANS = 1024;
constexpr int SUB = 32;                 // fp16 prefix re-base granularity
constexpr int SERVE = 128;              // starts served per chunk
constexpr int LOAD_ROWS = 160;          // SERVE + 32
constexpr int NCHUNK = 32;              // 4064/128 -> 32 chunks cover starts 0..4095
constexpr int NWG = B * NCHUNK;         // 256 workgroups
constexpr int NTHREADS = 640;           // 10 waves x 16 rows = 160
constexpr int LIST_CAP = 128;           // mean 32 spans/chunk, sd ~5.6

typedef float vfloat4 __attribute__((ext_vector_type(4)));

__device__ __forceinline__ float4 f4add(float4 a, float4 b) {
    a.x += b.x; a.y += b.y; a.z += b.z; a.w += b.w; return a;
}

__global__ __launch_bounds__(NTHREADS, 1) void fused_span_avg_kernel(
    const float* __restrict__ seq,   // [B, S, D]
    const int*   __restrict__ idx32, // [B, N_SPANS, 2] int32 or int64 words
    float*       __restrict__ out)   // [B, N_SPANS, D]
{
    const int gid  = blockIdx.x;
    const int b    = gid & (B - 1);      // batch = gid%8 -> per-XCD L2 slab
    const int c    = gid >> 3;           // chunk 0..31
    const int tid  = threadIdx.x;
    const int wv   = tid >> 6;           // 0..9, owns 16 rows
    const int lane = tid & 63;           // owns d = 4*lane .. 4*lane+3

    __shared__ uint2  Pfx[5][SUB][64];   // fp16x4 prefixes per sub-block, 80 KB
    __shared__ float4 totals[10][64];    // per-wave 16-row totals, 10 KB
    __shared__ unsigned list[LIST_CAP];
    __shared__ int count;

    if (tid == 0) count = 0;
    __syncthreads();                     // nothing in flight; drain is free

    // ---- issue idx loads FIRST (oldest in vmcnt queue) ----
    const bool is64 = (idx32[1] == 0);   // int32-layout word1 = end(span0) >= 1
    const int n0 = tid;                              // < 1024 always (tid<640)
    const int n1 = (tid + NTHREADS < N_SPANS) ? tid + NTHREADS : N_SPANS - 1;
    int4 w0, w1;
    {
        const size_t s0 = (size_t)b * N_SPANS + n0;
        const size_t s1 = (size_t)b * N_SPANS + n1;
        if (is64) {
            w0 = *((const int4*)idx32 + s0);
            w1 = *((const int4*)idx32 + s1);
        } else {
            const int2 a0 = *((const int2*)idx32 + s0);
            const int2 a1 = *((const int2*)idx32 + s1);
            w0 = make_int4(a0.x, 0, a0.y, 0);
            w1 = make_int4(a1.x, 0, a1.y, 0);
        }
    }

    // ---- then issue my 16 seq row loads (younger; not drained by idx use) --
    const int base_start = c * SERVE;
    int row0 = base_start + wv * 16;
    if (row0 > S - 16) row0 = S - 16;    // chunk 31's unused sub-4 rows only
    const float4* src = reinterpret_cast<const float4*>(
        seq + ((size_t)b * S + row0) * D) + lane;
    float4 p[16];
    #pragma unroll
    for (int j = 0; j < 16; ++j) p[j] = src[(size_t)j * (D / 4)];

    // ---- phase 2: filter my 2 spans (consumes only idx words) ----
    #pragma unroll
    for (int k = 0; k < 2; ++k) {
        const int n     = k ? n1 : n0;
        const bool live = k ? (tid + NTHREADS < N_SPANS) : true;
        const int start = k ? w1.x : w0.x;
        const int end   = k ? w1.z : w0.z;
        const int rs    = start - base_start;
        if (live && (unsigned)rs < (unsigned)SERVE) {
            const int w  = end - start;          // 1..32
            const int jb = rs + w - 1;           // 0..158
            const unsigned pk = (unsigned)n | ((unsigned)rs << 10) |
                                ((unsigned)jb << 18) | ((unsigned)(w - 1) << 26);
            const int slot = atomicAdd(&count, 1);
            if (slot < LIST_CAP) list[slot] = pk;
        }
    }

    // ---- phase 1b: in-register inclusive prefix over my 16 rows ----
    #pragma unroll
    for (int j = 1; j < 16; ++j) p[j] = f4add(p[j], p[j - 1]);
    totals[wv][lane] = p[15];
    __syncthreads();                     // totals + list complete

    float4 off = make_float4(0.f, 0.f, 0.f, 0.f);
    if (wv & 1) off = totals[wv - 1][lane];     // partner's 16-row total
    const int sub = wv >> 1;                    // 0..4

    #pragma unroll
    for (int j = 0; j < 16; ++j) {
        const float4 s = f4add(p[j], off);
        union { __half2 h[2]; uint2 u; } pk2;
        pk2.h[0] = __floats2half2_rn(s.x, s.y);
        pk2.h[1] = __floats2half2_rn(s.z, s.w);
        Pfx[sub][(wv & 1) * 16 + j][lane] = pk2.u;  // 8B/lane, 2-way alias (free)
    }
    __syncthreads();                     // Pfx ready

    // ---- phase 3: serve spans (10 waves round-robin) ----
    auto rd = [&](int s_, int j) -> float4 {
        union { uint2 u; __half2 h[2]; } pk2;
        pk2.u = Pfx[s_][j][lane];
        const float2 a = __half22float2(pk2.h[0]);
        const float2 cc = __half22float2(pk2.h[1]);
        return make_float4(a.x, a.y, cc.x, cc.y);
    };

    const int cnt = (count < LIST_CAP) ? count : LIST_CAP;
    for (int i = wv; i < cnt; i += 10) {
        const unsigned e = list[i];
        const int n  = e & 1023;
        const int ja = (e >> 10) & 255;          // 0..127
        const int jb = (e >> 18) & 255;          // 0..158
        const int w  = (int)((e >> 26) & 31) + 1;
        const int subA = ja >> 5, ia = ja & 31;
        const int subB = jb >> 5, ib = jb & 31;

        float4 s = rd(subB, ib);
        if (subB > subA) s = f4add(s, rd(subA, SUB - 1));
        if (ia) {
            const float4 t = rd(subA, ia - 1);
            s.x -= t.x; s.y -= t.y; s.z -= t.z; s.w -= t.w;
        }
        const float inv = 1.0f / (float)w;
        vfloat4 sv;
        sv.x = s.x * inv; sv.y = s.y * inv; sv.z = s.z * inv; sv.w = s.w * inv;
        vfloat4* dst = (vfloat4*)(out + ((size_t)b * N_SPANS + n) * D) + lane;
        __builtin_nontemporal_store(sv, dst);   // don't evict seq from L2
    }
}

extern "C" void kernel_launch(void* const* d_in, const int* in_sizes, int n_in,
                              void* d_out, int out_size, void* d_ws, size_t ws_size,
                              hipStream_t stream) {
    const float* seq = (const float*)d_in[0];
    const int*   idx = (const int*)d_in[1];
    float*       out = (float*)d_out;

    fused_span_avg_kernel<<<NWG, NTHREADS, 0, stream>>>(seq, idx, out);
}